// Round 3
// baseline (1040.720 us; speedup 1.0000x reference)
//
#include <hip/hip_runtime.h>

#define K 8192
#define NROWS 8192
#define NSTEPS 100
#define QEPS 1.1920928955078125e-07f

__global__ __launch_bounds__(256) void mse_observer_kernel(
    const float* __restrict__ x, float* __restrict__ out)
{
    const int row  = blockIdx.x;
    const int tid  = threadIdx.x;
    const int lane = tid & 63;
    const int wave = tid >> 6;

    const float4* xr = reinterpret_cast<const float4*>(x + (size_t)row * K);

    // Load 32 elements per thread (8 x float4, coalesced), keep in registers.
    float xv[32];
    #pragma unroll
    for (int j = 0; j < 8; ++j) {
        float4 v = xr[tid + j * 256];
        xv[j * 4 + 0] = v.x;
        xv[j * 4 + 1] = v.y;
        xv[j * 4 + 2] = v.z;
        xv[j * 4 + 3] = v.w;
    }
    // PIN in VGPRs: the empty asm *defines* each value, so the compiler cannot
    // rematerialize the (invariant) global loads inside the 100-step loop.
    // Without this, LLVM sinks the loads into the loop (VGPR_Count was 28!)
    // and we pay 100x re-read through L2 instead of register reads.
    #pragma unroll
    for (int e = 0; e < 32; ++e) asm volatile("" : "+v"(xv[e]));

    // Per-thread min/max
    float vmin = xv[0], vmax = xv[0];
    #pragma unroll
    for (int e = 1; e < 32; ++e) {
        vmin = fminf(vmin, xv[e]);
        vmax = fmaxf(vmax, xv[e]);
    }
    // Wave (64-lane) reduce
    #pragma unroll
    for (int off = 32; off >= 1; off >>= 1) {
        vmin = fminf(vmin, __shfl_xor(vmin, off));
        vmax = fmaxf(vmax, __shfl_xor(vmax, off));
    }

    __shared__ float smin[4], smax[4];
    __shared__ float partial[NSTEPS * 4];
    __shared__ float sloss[NSTEPS];

    if (lane == 0) { smin[wave] = vmin; smax[wave] = vmax; }
    __syncthreads();

    const float rmin  = fminf(fminf(smin[0], smin[1]), fminf(smin[2], smin[3]));
    const float rmax  = fmaxf(fmaxf(smax[0], smax[1]), fmaxf(smax[2], smax[3]));
    const float range = fmaxf(fabsf(rmin), rmax);
    const float rstep = range / (float)NSTEPS;   // matches range_val / STEPS

    // 100 candidate thresholds; loss accumulated per wave, stored to LDS.
    for (int i = 1; i <= NSTEPS; ++i) {
        const float thres = rstep * (float)i;
        const float s     = fmaxf(thres / 127.5f, QEPS);
        const float inv_s = 1.0f / s;
        float acc0 = 0.0f, acc1 = 0.0f;   // 2 chains: hide FMA dep latency
        #pragma unroll
        for (int e = 0; e < 32; e += 2) {
            float q0 = __builtin_amdgcn_fmed3f(
                __builtin_rintf(xv[e] * inv_s), -128.0f, 127.0f);
            float d0 = __builtin_fmaf(q0, s, -xv[e]);
            acc0 = __builtin_fmaf(d0, d0, acc0);
            float q1 = __builtin_amdgcn_fmed3f(
                __builtin_rintf(xv[e + 1] * inv_s), -128.0f, 127.0f);
            float d1 = __builtin_fmaf(q1, s, -xv[e + 1]);
            acc1 = __builtin_fmaf(d1, d1, acc1);
        }
        float acc = acc0 + acc1;
        // Wave reduce sum
        #pragma unroll
        for (int off = 32; off >= 1; off >>= 1) acc += __shfl_xor(acc, off);
        if (lane == 0) partial[(i - 1) * 4 + wave] = acc;  // own slot, no race
    }
    __syncthreads();

    // Combine wave partials (sum over row; mean = sum * 2^-13 exact, argmin same)
    if (tid < NSTEPS) {
        sloss[tid] = (partial[tid * 4 + 0] + partial[tid * 4 + 1]) +
                     (partial[tid * 4 + 2] + partial[tid * 4 + 3]);
    }
    __syncthreads();

    if (tid == 0) {
        float opt = 3.4e38f;
        int best = 0;
        #pragma unroll 1
        for (int i = 0; i < NSTEPS; ++i) {
            float l = sloss[i];
            if (l < opt) { opt = l; best = i; }   // strict <: earliest min
        }
        const float tbest = rstep * (float)(best + 1);
        out[row]         = -tbest;   // min_val
        out[NROWS + row] =  tbest;   // max_val
    }
}

extern "C" void kernel_launch(void* const* d_in, const int* in_sizes, int n_in,
                              void* d_out, int out_size, void* d_ws, size_t ws_size,
                              hipStream_t stream) {
    const float* x = (const float*)d_in[0];
    float* out = (float*)d_out;
    mse_observer_kernel<<<NROWS, 256, 0, stream>>>(x, out);
}

// Round 7
// 883.643 us; speedup vs baseline: 1.1778x; 1.1778x over previous
//
#include <hip/hip_runtime.h>

#define K 8192
#define NROWS 8192
#define NSTEPS 100
#define QEPS 1.1920928955078125e-07f

// __launch_bounds__(256, 4): min 4 waves/EU -> VGPR budget 128. Without the
// second arg the allocator targets 8 waves/EU (64 VGPR) and demotes the
// 32-element per-thread row chunk to scratch (VGPR_Count=28, ~900us from
// 100x scratch reloads through L2). asm "+v" pins cannot fix a spill.
__global__ __launch_bounds__(256, 4) void mse_observer_kernel(
    const float* __restrict__ x, float* __restrict__ out)
{
    const int row  = blockIdx.x;
    const int tid  = threadIdx.x;
    const int lane = tid & 63;
    const int wave = tid >> 6;

    const float4* __restrict__ xr =
        reinterpret_cast<const float4*>(x + (size_t)row * K);

    // 32 elements/thread in 8 NAMED float4s — no indexable aggregate, so
    // there is nothing for the compiler to demote to scratch.
    float4 v0 = xr[tid +    0];
    float4 v1 = xr[tid +  256];
    float4 v2 = xr[tid +  512];
    float4 v3 = xr[tid +  768];
    float4 v4 = xr[tid + 1024];
    float4 v5 = xr[tid + 1280];
    float4 v6 = xr[tid + 1536];
    float4 v7 = xr[tid + 1792];

    // Per-thread min/max
    float vmin = fminf(fminf(v0.x, v0.y), fminf(v0.z, v0.w));
    float vmax = fmaxf(fmaxf(v0.x, v0.y), fmaxf(v0.z, v0.w));
#define MM4(v) do { \
        vmin = fminf(vmin, fminf(fminf(v.x, v.y), fminf(v.z, v.w))); \
        vmax = fmaxf(vmax, fmaxf(fmaxf(v.x, v.y), fmaxf(v.z, v.w))); } while (0)
    MM4(v1); MM4(v2); MM4(v3); MM4(v4); MM4(v5); MM4(v6); MM4(v7);
#undef MM4

    // Wave (64-lane) reduce
    #pragma unroll
    for (int off = 32; off >= 1; off >>= 1) {
        vmin = fminf(vmin, __shfl_xor(vmin, off));
        vmax = fmaxf(vmax, __shfl_xor(vmax, off));
    }

    __shared__ float  smin[4], smax[4];
    __shared__ float2 sitab[NSTEPS];      // (s, 1/s) per step
    __shared__ float  partial[NSTEPS * 4];
    __shared__ float  sloss[NSTEPS];

    if (lane == 0) { smin[wave] = vmin; smax[wave] = vmax; }
    __syncthreads();

    const float rmin  = fminf(fminf(smin[0], smin[1]), fminf(smin[2], smin[3]));
    const float rmax  = fmaxf(fmaxf(smax[0], smax[1]), fmaxf(smax[2], smax[3]));
    const float range = fmaxf(fabsf(rmin), rmax);
    const float rstep = range / (float)NSTEPS;   // matches range_val / STEPS

    // Precompute per-step scale table once (kills per-step v_rcp+Newton).
    if (tid < NSTEPS) {
        const float thres = rstep * (float)(tid + 1);
        const float s     = fmaxf(thres / 127.5f, QEPS);
        sitab[tid] = make_float2(s, 1.0f / s);
    }
    __syncthreads();

    for (int i = 0; i < NSTEPS; ++i) {
        const float2 si   = sitab[i];     // broadcast ds_read_b64
        const float s     = si.x;
        const float inv_s = si.y;
        float acc0 = 0.0f, acc1 = 0.0f;   // 2 chains: hide FMA dep latency
#define QE(val, acc) do { \
        float q = __builtin_amdgcn_fmed3f( \
            __builtin_rintf((val) * inv_s), -128.0f, 127.0f); \
        float d = __builtin_fmaf(q, s, -(val)); \
        acc = __builtin_fmaf(d, d, acc); } while (0)
        QE(v0.x, acc0); QE(v0.y, acc1); QE(v0.z, acc0); QE(v0.w, acc1);
        QE(v1.x, acc0); QE(v1.y, acc1); QE(v1.z, acc0); QE(v1.w, acc1);
        QE(v2.x, acc0); QE(v2.y, acc1); QE(v2.z, acc0); QE(v2.w, acc1);
        QE(v3.x, acc0); QE(v3.y, acc1); QE(v3.z, acc0); QE(v3.w, acc1);
        QE(v4.x, acc0); QE(v4.y, acc1); QE(v4.z, acc0); QE(v4.w, acc1);
        QE(v5.x, acc0); QE(v5.y, acc1); QE(v5.z, acc0); QE(v5.w, acc1);
        QE(v6.x, acc0); QE(v6.y, acc1); QE(v6.z, acc0); QE(v6.w, acc1);
        QE(v7.x, acc0); QE(v7.y, acc1); QE(v7.z, acc0); QE(v7.w, acc1);
#undef QE
        float acc = acc0 + acc1;
        // Wave reduce sum
        #pragma unroll
        for (int off = 32; off >= 1; off >>= 1) acc += __shfl_xor(acc, off);
        if (lane == 0) partial[i * 4 + wave] = acc;   // own slot, no race
    }
    __syncthreads();

    // Combine wave partials (sum over row; mean = sum * 2^-13 exact, argmin same)
    if (tid < NSTEPS) {
        sloss[tid] = (partial[tid * 4 + 0] + partial[tid * 4 + 1]) +
                     (partial[tid * 4 + 2] + partial[tid * 4 + 3]);
    }
    __syncthreads();

    if (tid == 0) {
        float opt = 3.4e38f;
        int best = 0;
        #pragma unroll 1
        for (int i = 0; i < NSTEPS; ++i) {
            float l = sloss[i];
            if (l < opt) { opt = l; best = i; }   // strict <: earliest min
        }
        const float tbest = rstep * (float)(best + 1);
        out[row]         = -tbest;   // min_val
        out[NROWS + row] =  tbest;   // max_val
    }
}

extern "C" void kernel_launch(void* const* d_in, const int* in_sizes, int n_in,
                              void* d_out, int out_size, void* d_ws, size_t ws_size,
                              hipStream_t stream) {
    const float* x = (const float*)d_in[0];
    float* out = (float*)d_out;
    mse_observer_kernel<<<NROWS, 256, 0, stream>>>(x, out);
}